// Round 1
// baseline (406.402 us; speedup 1.0000x reference)
//
#include <hip/hip_runtime.h>
#include <hip/hip_bf16.h>

// Problem constants
#define BATCH 16384
#define K1DIM 3072
#define NCOUNT 8
#define NO 16        // L2+1 outputs of layer-1 per selected stack
#define BKC 768      // K-chunk staged in LDS (16 rows x 768 f32 = 48 KB)

__host__ __device__ constexpr int brev6(int i) {
    int r = 0;
    for (int b = 0; b < 6; ++b) r |= ((i >> b) & 1) << (5 - b);
    return r;
}

// ---------------- K1: bucket samples by idx (LDS histogram) ----------------
__global__ __launch_bounds__(256) void k_bucket(const int* __restrict__ ls,
                                                int* __restrict__ counts,
                                                int* __restrict__ bucketArr) {
    __shared__ int h[NCOUNT];
    __shared__ int hbase[NCOUNT];
    int t = threadIdx.x;
    if (t < NCOUNT) h[t] = 0;
    __syncthreads();
    int i = blockIdx.x * 256 + t;
    int idx = ls[i];
    int lpos = atomicAdd(&h[idx], 1);
    __syncthreads();
    if (t < NCOUNT) hbase[t] = atomicAdd(&counts[t], h[t]);
    __syncthreads();
    bucketArr[idx * BATCH + hbase[idx] + lpos] = i;
}

// ---------------- K2: block scheduling prefix over bucket counts -----------
__global__ void k_sched(const int* __restrict__ counts, int* __restrict__ blkoff) {
    if (threadIdx.x == 0) {
        int acc = 0;
        for (int i = 0; i < NCOUNT; ++i) {
            blkoff[i] = acc;
            acc += (counts[i] + 15) >> 4;   // 16 samples per block
        }
        blkoff[NCOUNT] = acc;
    }
}

// ---------------- K3: main gather-GEMM  y[s][0..15] ------------------------
// block = 256 thr (4 waves); wave = 4 samples x 16 outputs, k spread on lanes.
__global__ __launch_bounds__(256, 3) void k_gemm(
    const float* __restrict__ x,
    const float* __restrict__ l1w, const float* __restrict__ l1fw,
    const float* __restrict__ l1b, const float* __restrict__ l1fb,
    const int* __restrict__ bucketArr, const int* __restrict__ counts,
    const int* __restrict__ blkoff, float* __restrict__ y) {
    __shared__ float Wl[NO * BKC];     // 48 KB, combined (l1_w + l1f_w) chunk

    int b = blockIdx.x;
    if (b >= blkoff[NCOUNT]) return;
    int bucket = 0;
#pragma unroll
    for (int i = 1; i < NCOUNT; ++i)
        if (b >= blkoff[i]) bucket = i;
    int chunk = b - blkoff[bucket];
    int count = counts[bucket];

    int t = threadIdx.x;
    int lane = t & 63;
    int wid = t >> 6;

    const int* bk = bucketArr + bucket * BATCH;
    int base = chunk * 16 + wid * 4;
    int g0 = min(base + 0, count - 1);
    int g1 = min(base + 1, count - 1);
    int g2 = min(base + 2, count - 1);
    int g3 = min(base + 3, count - 1);
    int sid0 = bk[g0], sid1 = bk[g1], sid2 = bk[g2], sid3 = bk[g3];
    const float* xr0 = x + (size_t)sid0 * K1DIM;
    const float* xr1 = x + (size_t)sid1 * K1DIM;
    const float* xr2 = x + (size_t)sid2 * K1DIM;
    const float* xr3 = x + (size_t)sid3 * K1DIM;

    float acc[64];
#pragma unroll
    for (int i = 0; i < 64; ++i) acc[i] = 0.f;

    const float* wstack = l1w + (size_t)bucket * NO * K1DIM;

    for (int kk = 0; kk < K1DIM; kk += BKC) {
        __syncthreads();
        // stage combined weights: 16 x 768 f32 = 3072 float4; 12 per thread
#pragma unroll
        for (int i = 0; i < 12; ++i) {
            int f4 = t + i * 256;          // float4 index in [0,3072)
            int r = f4 / 192;              // row 0..15  (192 float4 per row)
            int c = (f4 - r * 192) * 4;    // col in floats 0..764
            float4 a = *(const float4*)(wstack + (size_t)r * K1DIM + kk + c);
            float4 f = *(const float4*)(l1fw + (size_t)r * K1DIM + kk + c);
            float4 w;
            w.x = a.x + f.x; w.y = a.y + f.y; w.z = a.z + f.z; w.w = a.w + f.w;
            *(float4*)&Wl[r * BKC + c] = w;
        }
        __syncthreads();

#pragma unroll
        for (int it = 0; it < 3; ++it) {
            int k = kk + it * 256 + lane * 4;
            float4 xv0 = *(const float4*)(xr0 + k);
            float4 xv1 = *(const float4*)(xr1 + k);
            float4 xv2 = *(const float4*)(xr2 + k);
            float4 xv3 = *(const float4*)(xr3 + k);
            int wbase = it * 256 + lane * 4;
#pragma unroll
            for (int o = 0; o < NO; ++o) {
                float4 wv = *(const float4*)&Wl[o * BKC + wbase];
#define ACCUM(S, XV)                                                     \
                {                                                        \
                    float& a_ = acc[brev6((S)*16 + o)];                  \
                    a_ = fmaf(XV.x, wv.x, a_);                           \
                    a_ = fmaf(XV.y, wv.y, a_);                           \
                    a_ = fmaf(XV.z, wv.z, a_);                           \
                    a_ = fmaf(XV.w, wv.w, a_);                           \
                }
                ACCUM(0, xv0) ACCUM(1, xv1) ACCUM(2, xv2) ACCUM(3, xv3)
#undef ACCUM
            }
        }
    }

    // butterfly cross-lane reduce: 64 partial sums -> lane l holds pair l
#pragma unroll
    for (int st = 0; st < 6; ++st) {
        const int m = 1 << st;
        const int half = 32 >> st;
        const bool hi = (lane & m) != 0;
#pragma unroll
        for (int i = 0; i < half; ++i) {
            float mine = hi ? acc[i] : acc[i + half];
            float other = __shfl_xor(mine, m, 64);
            float keep = hi ? acc[i + half] : acc[i];
            acc[i] = keep + other;
        }
    }

    // lane l = (sample l>>4, output l&15)
    int p_s = lane >> 4;
    int p_o = lane & 15;
    int gp = min(base + p_s, count - 1);
    int sid = bk[gp];
    float bias = l1b[bucket * NO + p_o] + l1fb[p_o];
    y[(size_t)sid * NO + p_o] = acc[0] + bias;
}

// ---------------- K4: tail MLP (30 -> 32 -> 1) per sample ------------------
__global__ __launch_bounds__(128) void k_tail(
    const float* __restrict__ y, const int* __restrict__ ls,
    const float* __restrict__ l2w, const float* __restrict__ l2b,
    const float* __restrict__ outw, const float* __restrict__ outb,
    float* __restrict__ out) {
    int s = blockIdx.x * 128 + threadIdx.x;
    int idx = ls[s];
    const float4* yp = (const float4*)(y + (size_t)s * NO);
    float4 a0 = yp[0], a1 = yp[1], a2 = yp[2], a3 = yp[3];
    float v[16] = {a0.x, a0.y, a0.z, a0.w, a1.x, a1.y, a1.z, a1.w,
                   a2.x, a2.y, a2.z, a2.w, a3.x, a3.y, a3.z, a3.w};
    float l1x[30];
#pragma unroll
    for (int j = 0; j < 15; ++j) {
        float tv = v[j];
        float sq = tv * tv * (127.f / 128.f);
        l1x[j] = fminf(fmaxf(sq, 0.f), 1.f);
        l1x[j + 15] = fminf(fmaxf(tv, 0.f), 1.f);
    }
    const float* w2 = l2w + (size_t)idx * 32 * 30;
    const float* b2 = l2b + idx * 32;
    const float* ow = outw + idx * 32;
    float r = outb[idx];
#pragma unroll 4
    for (int o2 = 0; o2 < 32; ++o2) {
        float tacc = b2[o2];
        const float* wr = w2 + o2 * 30;
#pragma unroll
        for (int j = 0; j < 15; ++j) {
            float2 wp = *(const float2*)(wr + j * 2);
            tacc = fmaf(l1x[j * 2], wp.x, tacc);
            tacc = fmaf(l1x[j * 2 + 1], wp.y, tacc);
        }
        tacc = fminf(fmaxf(tacc, 0.f), 1.f);
        r = fmaf(tacc, ow[o2], r);
    }
    out[s] = r + v[15];
}

// ---------------- launch ---------------------------------------------------
extern "C" void kernel_launch(void* const* d_in, const int* in_sizes, int n_in,
                              void* d_out, int out_size, void* d_ws, size_t ws_size,
                              hipStream_t stream) {
    const float* x    = (const float*)d_in[0];
    const int*   ls   = (const int*)  d_in[1];
    const float* l1w  = (const float*)d_in[2];
    const float* l1b  = (const float*)d_in[3];
    const float* l1fw = (const float*)d_in[4];
    const float* l1fb = (const float*)d_in[5];
    const float* l2w  = (const float*)d_in[6];
    const float* l2b  = (const float*)d_in[7];
    const float* outw = (const float*)d_in[8];
    const float* outb = (const float*)d_in[9];
    float* out = (float*)d_out;

    char* ws = (char*)d_ws;
    float* y        = (float*)ws;                        // 16384*16*4 = 1 MB
    int*   bucketArr= (int*)(ws + 1048576);              // 8*16384*4 = 512 KB
    int*   counts   = (int*)(ws + 1048576 + 524288);     // 8 ints
    int*   blkoff   = (int*)(ws + 1048576 + 524288 + 32);// 9 ints

    hipMemsetAsync(counts, 0, 32, stream);
    k_bucket<<<BATCH / 256, 256, 0, stream>>>(ls, counts, bucketArr);
    k_sched<<<1, 64, 0, stream>>>(counts, blkoff);
    // max blocks = 1024 + 7 (ceil rounding across 8 buckets)
    k_gemm<<<1031, 256, 0, stream>>>(x, l1w, l1fw, l1b, l1fb,
                                     bucketArr, counts, blkoff, y);
    k_tail<<<BATCH / 128, 128, 0, stream>>>(y, ls, l2w, l2b, outw, outb, out);
}

// Round 6
// 384.171 us; speedup vs baseline: 1.0579x; 1.0579x over previous
//
#include <hip/hip_runtime.h>
#include <hip/hip_bf16.h>

// Problem constants
#define BATCH 16384
#define K1DIM 3072
#define NCOUNT 8
#define NO 16        // L2+1 outputs of layer-1 per selected stack

typedef float f32x4 __attribute__((ext_vector_type(4)));  // native vector for nontemporal builtins

__host__ __device__ constexpr int brev6(int i) {
    int r = 0;
    for (int b = 0; b < 6; ++b) r |= ((i >> b) & 1) << (5 - b);
    return r;
}

// ---------------- K0: precombine weights  wc = l1_w[stack] + l1f_w --------
__global__ __launch_bounds__(256) void k_combine(const float* __restrict__ l1w,
                                                 const float* __restrict__ l1fw,
                                                 float* __restrict__ wc) {
    int i = blockIdx.x * 256 + threadIdx.x;   // float4 index, 98304 total
    int row = i / 768;                        // 0..127  (stack*16 + o)
    int col = (i - row * 768) * 4;            // float col
    int o = row & 15;
    f32x4 a = *(const f32x4*)(l1w + (size_t)row * K1DIM + col);
    f32x4 f = *(const f32x4*)(l1fw + (size_t)o * K1DIM + col);
    *(f32x4*)(wc + (size_t)row * K1DIM + col) = a + f;
}

// ---------------- K1: bucket samples by idx (LDS histogram) ----------------
__global__ __launch_bounds__(256) void k_bucket(const int* __restrict__ ls,
                                                int* __restrict__ counts,
                                                int* __restrict__ bucketArr) {
    __shared__ int h[NCOUNT];
    __shared__ int hbase[NCOUNT];
    int t = threadIdx.x;
    if (t < NCOUNT) h[t] = 0;
    __syncthreads();
    int i = blockIdx.x * 256 + t;
    int idx = ls[i];
    int lpos = atomicAdd(&h[idx], 1);
    __syncthreads();
    if (t < NCOUNT) hbase[t] = atomicAdd(&counts[t], h[t]);
    __syncthreads();
    bucketArr[idx * BATCH + hbase[idx] + lpos] = i;
}

// ---------------- K2: block scheduling prefix over bucket counts -----------
__global__ void k_sched(const int* __restrict__ counts, int* __restrict__ blkoff) {
    if (threadIdx.x == 0) {
        int acc = 0;
        for (int i = 0; i < NCOUNT; ++i) {
            blkoff[i] = acc;
            acc += (counts[i] + 15) >> 4;   // 16 samples per block
        }
        blkoff[NCOUNT] = acc;
    }
}

// ---------------- K3: main gather-GEMM  y[s][0..15] ------------------------
// block = 256 thr (4 waves); wave = 4 samples x 16 outputs, k spread on lanes.
// No LDS: weights (192 KB/bucket) come from L2; x streamed nontemporal.
__global__ __launch_bounds__(256) void k_gemm(
    const float* __restrict__ x, const float* __restrict__ wc_all,
    const float* __restrict__ l1b, const float* __restrict__ l1fb,
    const int* __restrict__ bucketArr, const int* __restrict__ counts,
    const int* __restrict__ blkoff, float* __restrict__ y) {
    int b = blockIdx.x;
    if (b >= blkoff[NCOUNT]) return;
    int bucket = 0;
#pragma unroll
    for (int i = 1; i < NCOUNT; ++i)
        if (b >= blkoff[i]) bucket = i;
    int chunk = b - blkoff[bucket];
    int count = counts[bucket];

    int t = threadIdx.x;
    int lane = t & 63;
    int wid = t >> 6;

    const int* bk = bucketArr + bucket * BATCH;
    int base = chunk * 16 + wid * 4;
    int g0 = min(base + 0, count - 1);
    int g1 = min(base + 1, count - 1);
    int g2 = min(base + 2, count - 1);
    int g3 = min(base + 3, count - 1);
    int sid0 = bk[g0], sid1 = bk[g1], sid2 = bk[g2], sid3 = bk[g3];
    const float* xr0 = x + (size_t)sid0 * K1DIM + lane * 4;
    const float* xr1 = x + (size_t)sid1 * K1DIM + lane * 4;
    const float* xr2 = x + (size_t)sid2 * K1DIM + lane * 4;
    const float* xr3 = x + (size_t)sid3 * K1DIM + lane * 4;
    const float* wp = wc_all + (size_t)bucket * NO * K1DIM + lane * 4;

    float acc[64];
#pragma unroll
    for (int i = 0; i < 64; ++i) acc[i] = 0.f;

#pragma unroll 2
    for (int it = 0; it < K1DIM / 256; ++it) {
        int k = it * 256;
        f32x4 xv0 = __builtin_nontemporal_load((const f32x4*)(xr0 + k));
        f32x4 xv1 = __builtin_nontemporal_load((const f32x4*)(xr1 + k));
        f32x4 xv2 = __builtin_nontemporal_load((const f32x4*)(xr2 + k));
        f32x4 xv3 = __builtin_nontemporal_load((const f32x4*)(xr3 + k));
#pragma unroll
        for (int o = 0; o < NO; ++o) {
            f32x4 wv = *(const f32x4*)(wp + o * K1DIM + k);
#define ACCUM(S, XV)                                                     \
            {                                                            \
                float& a_ = acc[brev6((S)*16 + o)];                      \
                a_ = fmaf(XV.x, wv.x, a_);                               \
                a_ = fmaf(XV.y, wv.y, a_);                               \
                a_ = fmaf(XV.z, wv.z, a_);                               \
                a_ = fmaf(XV.w, wv.w, a_);                               \
            }
            ACCUM(0, xv0) ACCUM(1, xv1) ACCUM(2, xv2) ACCUM(3, xv3)
#undef ACCUM
        }
    }

    // butterfly cross-lane reduce: 64 partial sums -> lane l holds pair l
#pragma unroll
    for (int st = 0; st < 6; ++st) {
        const int m = 1 << st;
        const int half = 32 >> st;
        const bool hi = (lane & m) != 0;
#pragma unroll
        for (int i = 0; i < half; ++i) {
            float mine = hi ? acc[i] : acc[i + half];
            float other = __shfl_xor(mine, m, 64);
            float keep = hi ? acc[i + half] : acc[i];
            acc[i] = keep + other;
        }
    }

    // lane l = (sample l>>4, output l&15)
    int p_s = lane >> 4;
    int p_o = lane & 15;
    int gp = min(base + p_s, count - 1);
    int sid = bk[gp];
    float bias = l1b[bucket * NO + p_o] + l1fb[p_o];
    y[(size_t)sid * NO + p_o] = acc[0] + bias;
}

// ---------------- K4: tail MLP (30 -> 32 -> 1), 32 lanes per sample --------
__global__ __launch_bounds__(256) void k_tail(
    const float* __restrict__ y, const int* __restrict__ ls,
    const float* __restrict__ l2w, const float* __restrict__ l2b,
    const float* __restrict__ outw, const float* __restrict__ outb,
    float* __restrict__ out) {
    int gt = blockIdx.x * 256 + threadIdx.x;
    int s = gt >> 5;           // sample
    int o2 = gt & 31;          // hidden unit
    int idx = ls[s];
    const f32x4* yp = (const f32x4*)(y + (size_t)s * NO);
    f32x4 a0 = yp[0], a1 = yp[1], a2 = yp[2], a3 = yp[3];
    float v[16] = {a0.x, a0.y, a0.z, a0.w, a1.x, a1.y, a1.z, a1.w,
                   a2.x, a2.y, a2.z, a2.w, a3.x, a3.y, a3.z, a3.w};
    float l1x[30];
#pragma unroll
    for (int j = 0; j < 15; ++j) {
        float tv = v[j];
        float sq = tv * tv * (127.f / 128.f);
        l1x[j] = fminf(fmaxf(sq, 0.f), 1.f);
        l1x[j + 15] = fminf(fmaxf(tv, 0.f), 1.f);
    }
    const float* wr = l2w + (size_t)idx * 32 * 30 + o2 * 30;
    float tacc = l2b[idx * 32 + o2];
#pragma unroll
    for (int j = 0; j < 15; ++j) {
        float2 wpv = *(const float2*)(wr + j * 2);
        tacc = fmaf(l1x[j * 2], wpv.x, tacc);
        tacc = fmaf(l1x[j * 2 + 1], wpv.y, tacc);
    }
    tacc = fminf(fmaxf(tacc, 0.f), 1.f);
    float r = tacc * outw[idx * 32 + o2];
#pragma unroll
    for (int m = 1; m < 32; m <<= 1) r += __shfl_xor(r, m, 64);
    if (o2 == 0) out[s] = r + outb[idx] + v[15];
}

// ---------------- launch ---------------------------------------------------
extern "C" void kernel_launch(void* const* d_in, const int* in_sizes, int n_in,
                              void* d_out, int out_size, void* d_ws, size_t ws_size,
                              hipStream_t stream) {
    const float* x    = (const float*)d_in[0];
    const int*   ls   = (const int*)  d_in[1];
    const float* l1w  = (const float*)d_in[2];
    const float* l1b  = (const float*)d_in[3];
    const float* l1fw = (const float*)d_in[4];
    const float* l1fb = (const float*)d_in[5];
    const float* l2w  = (const float*)d_in[6];
    const float* l2b  = (const float*)d_in[7];
    const float* outw = (const float*)d_in[8];
    const float* outb = (const float*)d_in[9];
    float* out = (float*)d_out;

    char* ws = (char*)d_ws;
    float* wc       = (float*)ws;                       // 128*3072*4 = 1.5 MB
    float* y        = (float*)(ws + 1572864);           // 16384*16*4 = 1 MB
    int*   bucketArr= (int*)(ws + 1572864 + 1048576);   // 8*16384*4 = 512 KB
    int*   counts   = (int*)(ws + 1572864 + 1048576 + 524288);
    int*   blkoff   = (int*)(ws + 1572864 + 1048576 + 524288 + 64);

    (void)hipMemsetAsync(counts, 0, 64, stream);
    k_combine<<<384, 256, 0, stream>>>(l1w, l1fw, wc);
    k_bucket<<<BATCH / 256, 256, 0, stream>>>(ls, counts, bucketArr);
    k_sched<<<1, 64, 0, stream>>>(counts, blkoff);
    // max blocks = 1024 + 7 (ceil rounding across 8 buckets)
    k_gemm<<<1031, 256, 0, stream>>>(x, wc, l1b, l1fb,
                                     bucketArr, counts, blkoff, y);
    k_tail<<<BATCH * 32 / 256, 256, 0, stream>>>(y, ls, l2w, l2b, outw, outb, out);
}

// Round 7
// 351.896 us; speedup vs baseline: 1.1549x; 1.0917x over previous
//
#include <hip/hip_runtime.h>
#include <hip/hip_bf16.h>

// Problem constants
#define BATCH 16384
#define K1DIM 3072
#define NCOUNT 8
#define NO 16            // L2+1 outputs of layer-1 per selected stack
#define CHUNK 256        // floats of K per staged chunk (16 rows x 1 KB = 16 KB)
#define NCHUNK (K1DIM / CHUNK)   // 12

typedef float f32x4 __attribute__((ext_vector_type(4)));
typedef unsigned int u32;

__host__ __device__ constexpr int brev5(int i) {
    int r = 0;
    for (int b = 0; b < 5; ++b) r |= ((i >> b) & 1) << (4 - b);
    return r;
}

// ---------------- K0: precombine weights  wc = l1_w[stack] + l1f_w --------
__global__ __launch_bounds__(256) void k_combine(const float* __restrict__ l1w,
                                                 const float* __restrict__ l1fw,
                                                 float* __restrict__ wc) {
    int i = blockIdx.x * 256 + threadIdx.x;   // float4 index, 98304 total
    int row = i / 768;                        // 0..127  (stack*16 + o)
    int col = (i - row * 768) * 4;            // float col
    int o = row & 15;
    f32x4 a = *(const f32x4*)(l1w + (size_t)row * K1DIM + col);
    f32x4 f = *(const f32x4*)(l1fw + (size_t)o * K1DIM + col);
    *(f32x4*)(wc + (size_t)row * K1DIM + col) = a + f;
}

// ---------------- K1: bucket samples by idx (LDS histogram) ----------------
__global__ __launch_bounds__(256) void k_bucket(const int* __restrict__ ls,
                                                int* __restrict__ counts,
                                                int* __restrict__ bucketArr) {
    __shared__ int h[NCOUNT];
    __shared__ int hbase[NCOUNT];
    int t = threadIdx.x;
    if (t < NCOUNT) h[t] = 0;
    __syncthreads();
    int i = blockIdx.x * 256 + t;
    int idx = ls[i];
    int lpos = atomicAdd(&h[idx], 1);
    __syncthreads();
    if (t < NCOUNT) hbase[t] = atomicAdd(&counts[t], h[t]);
    __syncthreads();
    bucketArr[idx * BATCH + hbase[idx] + lpos] = i;
}

// ---------------- K3: main gather-GEMM  y[s][0..15] ------------------------
// 8 samples/block (2 per wave), K on lanes. Weights staged to LDS once per
// block via async global_load_lds (16 KB chunk, double-buffered).
__device__ __forceinline__ void stage4(const float* gbase, float* lds_linear,
                                       int wid, int lane) {
#pragma unroll
    for (int i = 0; i < 4; ++i) {
        int row = wid * 4 + i;
        const float* g = gbase + (size_t)row * K1DIM + lane * 4;
        float* l = lds_linear + row * CHUNK;   // wave-uniform base; HW adds lane*16
        __builtin_amdgcn_global_load_lds(
            (const __attribute__((address_space(1))) u32*)g,
            (__attribute__((address_space(3))) u32*)l, 16, 0, 0);
    }
}

__global__ __launch_bounds__(256, 5) void k_gemm(
    const float* __restrict__ x, const float* __restrict__ wc_all,
    const float* __restrict__ l1b, const float* __restrict__ l1fb,
    const int* __restrict__ bucketArr, const int* __restrict__ counts,
    float* __restrict__ y) {
    __shared__ float buf[2][NO * CHUNK];   // 2 x 16 KB

    // per-block prefix over bucket counts (replaces k_sched)
    int cnt[NCOUNT], off[NCOUNT];
    int nblk = 0;
#pragma unroll
    for (int i = 0; i < NCOUNT; ++i) {
        cnt[i] = counts[i];
        off[i] = nblk;
        nblk += (cnt[i] + 7) >> 3;        // 8 samples per block
    }
    int b = blockIdx.x;
    if (b >= nblk) return;
    int bucket = 0;
#pragma unroll
    for (int i = 1; i < NCOUNT; ++i) if (b >= off[i]) bucket = i;
    int chunkblk = b - off[bucket];
    int count = cnt[bucket];

    int t = threadIdx.x;
    int lane = t & 63;
    int wid = t >> 6;

    const int* bk = bucketArr + bucket * BATCH;
    int base = chunkblk * 8 + wid * 2;
    int g0 = min(base + 0, count - 1);
    int g1 = min(base + 1, count - 1);
    int sid0 = bk[g0], sid1 = bk[g1];
    const float* xr0 = x + (size_t)sid0 * K1DIM + lane * 4;
    const float* xr1 = x + (size_t)sid1 * K1DIM + lane * 4;
    const float* wstack = wc_all + (size_t)bucket * NO * K1DIM;

    float acc[32];
#pragma unroll
    for (int i = 0; i < 32; ++i) acc[i] = 0.f;

    stage4(wstack, &buf[0][0], wid, lane);   // chunk 0 -> buf[0]

    for (int it = 0; it < NCHUNK; ++it) {
        int cur = it & 1;
        __syncthreads();                     // buf[cur] staged (barrier drains vmcnt)
        if (it + 1 < NCHUNK)
            stage4(wstack + (it + 1) * CHUNK, &buf[cur ^ 1][0], wid, lane);
        int k = it * CHUNK;
        f32x4 xv0 = __builtin_nontemporal_load((const f32x4*)(xr0 + k));
        f32x4 xv1 = __builtin_nontemporal_load((const f32x4*)(xr1 + k));
        const float* lb = &buf[cur][lane * 4];
#pragma unroll
        for (int o = 0; o < NO; ++o) {
            f32x4 wv = *(const f32x4*)(lb + o * CHUNK);
            {
                float& a_ = acc[brev5(o)];
                a_ = fmaf(xv0.x, wv.x, a_);
                a_ = fmaf(xv0.y, wv.y, a_);
                a_ = fmaf(xv0.z, wv.z, a_);
                a_ = fmaf(xv0.w, wv.w, a_);
            }
            {
                float& a_ = acc[brev5(16 + o)];
                a_ = fmaf(xv1.x, wv.x, a_);
                a_ = fmaf(xv1.y, wv.y, a_);
                a_ = fmaf(xv1.z, wv.z, a_);
                a_ = fmaf(xv1.w, wv.w, a_);
            }
        }
    }

    // fold lane^32 pairs, then 5-stage butterfly: lane l<32 ends holding p=l
#pragma unroll
    for (int i = 0; i < 32; ++i) acc[i] += __shfl_xor(acc[i], 32, 64);
#pragma unroll
    for (int st = 0; st < 5; ++st) {
        const int m = 1 << st;
        const int half = 16 >> st;
        const bool hi = (lane & m) != 0;
#pragma unroll
        for (int i = 0; i < half; ++i) {
            float mine = hi ? acc[i] : acc[i + half];
            float other = __shfl_xor(mine, m, 64);
            float keep = hi ? acc[i + half] : acc[i];
            acc[i] = keep + other;
        }
    }

    if (lane < 32) {
        int p_s = lane >> 4;       // sample within wave (0..1)
        int p_o = lane & 15;       // output
        int gp = min(base + p_s, count - 1);
        int sid = bk[gp];
        float bias = l1b[bucket * NO + p_o] + l1fb[p_o];
        y[(size_t)sid * NO + p_o] = acc[0] + bias;
    }
}

// ---------------- K4: tail MLP (30 -> 32 -> 1), 32 lanes per sample --------
__global__ __launch_bounds__(256) void k_tail(
    const float* __restrict__ y, const int* __restrict__ ls,
    const float* __restrict__ l2w, const float* __restrict__ l2b,
    const float* __restrict__ outw, const float* __restrict__ outb,
    float* __restrict__ out) {
    int gt = blockIdx.x * 256 + threadIdx.x;
    int s = gt >> 5;           // sample
    int o2 = gt & 31;          // hidden unit
    int idx = ls[s];
    const f32x4* yp = (const f32x4*)(y + (size_t)s * NO);
    f32x4 a0 = yp[0], a1 = yp[1], a2 = yp[2], a3 = yp[3];
    float v[16] = {a0.x, a0.y, a0.z, a0.w, a1.x, a1.y, a1.z, a1.w,
                   a2.x, a2.y, a2.z, a2.w, a3.x, a3.y, a3.z, a3.w};
    float l1x[30];
#pragma unroll
    for (int j = 0; j < 15; ++j) {
        float tv = v[j];
        float sq = tv * tv * (127.f / 128.f);
        l1x[j] = fminf(fmaxf(sq, 0.f), 1.f);
        l1x[j + 15] = fminf(fmaxf(tv, 0.f), 1.f);
    }
    const float* wr = l2w + (size_t)idx * 32 * 30 + o2 * 30;
    float tacc = l2b[idx * 32 + o2];
#pragma unroll
    for (int j = 0; j < 15; ++j) {
        float2 wpv = *(const float2*)(wr + j * 2);
        tacc = fmaf(l1x[j * 2], wpv.x, tacc);
        tacc = fmaf(l1x[j * 2 + 1], wpv.y, tacc);
    }
    tacc = fminf(fmaxf(tacc, 0.f), 1.f);
    float r = tacc * outw[idx * 32 + o2];
#pragma unroll
    for (int m = 1; m < 32; m <<= 1) r += __shfl_xor(r, m, 64);
    if (o2 == 0) out[s] = r + outb[idx] + v[15];
}

// ---------------- launch ---------------------------------------------------
extern "C" void kernel_launch(void* const* d_in, const int* in_sizes, int n_in,
                              void* d_out, int out_size, void* d_ws, size_t ws_size,
                              hipStream_t stream) {
    const float* x    = (const float*)d_in[0];
    const int*   ls   = (const int*)  d_in[1];
    const float* l1w  = (const float*)d_in[2];
    const float* l1b  = (const float*)d_in[3];
    const float* l1fw = (const float*)d_in[4];
    const float* l1fb = (const float*)d_in[5];
    const float* l2w  = (const float*)d_in[6];
    const float* l2b  = (const float*)d_in[7];
    const float* outw = (const float*)d_in[8];
    const float* outb = (const float*)d_in[9];
    float* out = (float*)d_out;

    char* ws = (char*)d_ws;
    float* wc       = (float*)ws;                       // 128*3072*4 = 1.5 MB
    float* y        = (float*)(ws + 1572864);           // 16384*16*4 = 1 MB
    int*   bucketArr= (int*)(ws + 1572864 + 1048576);   // 8*16384*4 = 512 KB
    int*   counts   = (int*)(ws + 1572864 + 1048576 + 524288);

    (void)hipMemsetAsync(counts, 0, 32, stream);
    k_combine<<<384, 256, 0, stream>>>(l1w, l1fw, wc);
    k_bucket<<<BATCH / 256, 256, 0, stream>>>(ls, counts, bucketArr);
    // max blocks = 16384/8 + 7 (ceil rounding across 8 buckets)
    k_gemm<<<2055, 256, 0, stream>>>(x, wc, l1b, l1fb, bucketArr, counts, y);
    k_tail<<<BATCH * 32 / 256, 256, 0, stream>>>(y, ls, l2w, l2b, outw, outb, out);
}

// Round 8
// 329.030 us; speedup vs baseline: 1.2352x; 1.0695x over previous
//
#include <hip/hip_runtime.h>
#include <hip/hip_bf16.h>

// Problem constants
#define BATCH 16384
#define K1DIM 3072
#define NCOUNT 8
#define NO 16            // L2+1 outputs of layer-1 per selected stack
#define CHUNK 256        // floats of K per staged chunk (16 rows x 1 KB = 16 KB)
#define NCHUNK (K1DIM / CHUNK)   // 12
#define SPB 32           // samples per block (8 per wave)

typedef float f32x4 __attribute__((ext_vector_type(4)));
typedef unsigned int u32;

__host__ __device__ constexpr int brev6(int i) {
    int r = 0;
    for (int b = 0; b < 6; ++b) r |= ((i >> b) & 1) << (5 - b);
    return r;
}

// ---------------- K0: precombine weights  wc = l1_w[stack] + l1f_w --------
__global__ __launch_bounds__(256) void k_combine(const float* __restrict__ l1w,
                                                 const float* __restrict__ l1fw,
                                                 float* __restrict__ wc) {
    int i = blockIdx.x * 256 + threadIdx.x;   // float4 index, 98304 total
    int row = i / 768;                        // 0..127  (stack*16 + o)
    int col = (i - row * 768) * 4;            // float col
    int o = row & 15;
    f32x4 a = *(const f32x4*)(l1w + (size_t)row * K1DIM + col);
    f32x4 f = *(const f32x4*)(l1fw + (size_t)o * K1DIM + col);
    *(f32x4*)(wc + (size_t)row * K1DIM + col) = a + f;
}

// ---------------- K1: bucket samples by idx (LDS histogram) ----------------
__global__ __launch_bounds__(256) void k_bucket(const int* __restrict__ ls,
                                                int* __restrict__ counts,
                                                int* __restrict__ bucketArr) {
    __shared__ int h[NCOUNT];
    __shared__ int hbase[NCOUNT];
    int t = threadIdx.x;
    if (t < NCOUNT) h[t] = 0;
    __syncthreads();
    int i = blockIdx.x * 256 + t;
    int idx = ls[i];
    int lpos = atomicAdd(&h[idx], 1);
    __syncthreads();
    if (t < NCOUNT) hbase[t] = atomicAdd(&counts[t], h[t]);
    __syncthreads();
    bucketArr[idx * BATCH + hbase[idx] + lpos] = i;
}

// ---------------- K3: main gather-GEMM  y[s][0..15] ------------------------
// 32 samples/block (8 per wave), K on lanes. Weights staged to LDS once per
// block via async global_load_lds (16 KB chunk, double-buffered). 512 FMAs
// per wave per barrier interval hide the stage + x-load latency.
__device__ __forceinline__ void stage4(const float* gbase, float* lds_linear,
                                       int wid, int lane) {
#pragma unroll
    for (int i = 0; i < 4; ++i) {
        int row = wid * 4 + i;
        const float* g = gbase + (size_t)row * K1DIM + lane * 4;
        float* l = lds_linear + row * CHUNK;   // wave-uniform base; HW adds lane*16
        __builtin_amdgcn_global_load_lds(
            (const __attribute__((address_space(1))) u32*)g,
            (__attribute__((address_space(3))) u32*)l, 16, 0, 0);
    }
}

__global__ __launch_bounds__(256, 2) void k_gemm(
    const float* __restrict__ x, const float* __restrict__ wc_all,
    const float* __restrict__ l1b, const float* __restrict__ l1fb,
    const int* __restrict__ bucketArr, const int* __restrict__ counts,
    float* __restrict__ y) {
    __shared__ float buf[2][NO * CHUNK];   // 2 x 16 KB

    // per-block prefix over bucket counts
    int cnt[NCOUNT], off[NCOUNT];
    int nblk = 0;
#pragma unroll
    for (int i = 0; i < NCOUNT; ++i) {
        cnt[i] = counts[i];
        off[i] = nblk;
        nblk += (cnt[i] + SPB - 1) / SPB;
    }
    int b = blockIdx.x;
    if (b >= nblk) return;
    int bucket = 0;
#pragma unroll
    for (int i = 1; i < NCOUNT; ++i) if (b >= off[i]) bucket = i;
    int chunkblk = b - off[bucket];
    int count = cnt[bucket];

    int t = threadIdx.x;
    int lane = t & 63;
    int wid = t >> 6;

    const int* bk = bucketArr + bucket * BATCH;
    int base = chunkblk * SPB + wid * 8;
    const float* xr[8];
#pragma unroll
    for (int j = 0; j < 8; ++j) {
        int g = min(base + j, count - 1);
        xr[j] = x + (size_t)bk[g] * K1DIM + lane * 4;
    }
    const float* wstack = wc_all + (size_t)bucket * NO * K1DIM;

    float acc0[64], acc1[64];
#pragma unroll
    for (int i = 0; i < 64; ++i) { acc0[i] = 0.f; acc1[i] = 0.f; }

    stage4(wstack, &buf[0][0], wid, lane);   // chunk 0 -> buf[0]

    for (int it = 0; it < NCHUNK; ++it) {
        int cur = it & 1;
        __syncthreads();                     // buf[cur] staged
        if (it + 1 < NCHUNK)
            stage4(wstack + (it + 1) * CHUNK, &buf[cur ^ 1][0], wid, lane);
        int k = it * CHUNK;
        f32x4 xv[8];
#pragma unroll
        for (int j = 0; j < 8; ++j) xv[j] = *(const f32x4*)(xr[j] + k);
        const float* lb = &buf[cur][lane * 4];
#pragma unroll
        for (int o = 0; o < NO; ++o) {
            f32x4 wv = *(const f32x4*)(lb + o * CHUNK);
#define ACCUM(A, S, J)                                                   \
            {                                                            \
                float& a_ = A[brev6((S)*16 + o)];                        \
                a_ = fmaf(xv[J].x, wv.x, a_);                            \
                a_ = fmaf(xv[J].y, wv.y, a_);                            \
                a_ = fmaf(xv[J].z, wv.z, a_);                            \
                a_ = fmaf(xv[J].w, wv.w, a_);                            \
            }
            ACCUM(acc0, 0, 0) ACCUM(acc0, 1, 1) ACCUM(acc0, 2, 2) ACCUM(acc0, 3, 3)
            ACCUM(acc1, 0, 4) ACCUM(acc1, 1, 5) ACCUM(acc1, 2, 6) ACCUM(acc1, 3, 7)
#undef ACCUM
        }
    }

    // two 6-stage butterflies: lane l ends holding pair l of each 64-block
#pragma unroll
    for (int st = 0; st < 6; ++st) {
        const int m = 1 << st;
        const int half = 32 >> st;
        const bool hi = (lane & m) != 0;
#pragma unroll
        for (int i = 0; i < half; ++i) {
            float mine = hi ? acc0[i] : acc0[i + half];
            float other = __shfl_xor(mine, m, 64);
            float keep = hi ? acc0[i + half] : acc0[i];
            acc0[i] = keep + other;
            float mine1 = hi ? acc1[i] : acc1[i + half];
            float other1 = __shfl_xor(mine1, m, 64);
            float keep1 = hi ? acc1[i + half] : acc1[i];
            acc1[i] = keep1 + other1;
        }
    }

    // lane l = (sample l>>4, output l&15); block0 = samples base+0..3,
    // block1 = samples base+4..7
    int p_s = lane >> 4;
    int p_o = lane & 15;
    float bias = l1b[bucket * NO + p_o] + l1fb[p_o];
    {
        int gp = min(base + p_s, count - 1);
        y[(size_t)bk[gp] * NO + p_o] = acc0[0] + bias;
    }
    {
        int gp = min(base + 4 + p_s, count - 1);
        y[(size_t)bk[gp] * NO + p_o] = acc1[0] + bias;
    }
}

// ---------------- K4: tail MLP (30 -> 32 -> 1), 32 lanes per sample --------
__global__ __launch_bounds__(256) void k_tail(
    const float* __restrict__ y, const int* __restrict__ ls,
    const float* __restrict__ l2w, const float* __restrict__ l2b,
    const float* __restrict__ outw, const float* __restrict__ outb,
    float* __restrict__ out) {
    int gt = blockIdx.x * 256 + threadIdx.x;
    int s = gt >> 5;           // sample
    int o2 = gt & 31;          // hidden unit
    int idx = ls[s];
    const f32x4* yp = (const f32x4*)(y + (size_t)s * NO);
    f32x4 a0 = yp[0], a1 = yp[1], a2 = yp[2], a3 = yp[3];
    float v[16] = {a0.x, a0.y, a0.z, a0.w, a1.x, a1.y, a1.z, a1.w,
                   a2.x, a2.y, a2.z, a2.w, a3.x, a3.y, a3.z, a3.w};
    float l1x[30];
#pragma unroll
    for (int j = 0; j < 15; ++j) {
        float tv = v[j];
        float sq = tv * tv * (127.f / 128.f);
        l1x[j] = fminf(fmaxf(sq, 0.f), 1.f);
        l1x[j + 15] = fminf(fmaxf(tv, 0.f), 1.f);
    }
    const float* wr = l2w + (size_t)idx * 32 * 30 + o2 * 30;
    float tacc = l2b[idx * 32 + o2];
#pragma unroll
    for (int j = 0; j < 15; ++j) {
        float2 wpv = *(const float2*)(wr + j * 2);
        tacc = fmaf(l1x[j * 2], wpv.x, tacc);
        tacc = fmaf(l1x[j * 2 + 1], wpv.y, tacc);
    }
    tacc = fminf(fmaxf(tacc, 0.f), 1.f);
    float r = tacc * outw[idx * 32 + o2];
#pragma unroll
    for (int m = 1; m < 32; m <<= 1) r += __shfl_xor(r, m, 64);
    if (o2 == 0) out[s] = r + outb[idx] + v[15];
}

// ---------------- launch ---------------------------------------------------
extern "C" void kernel_launch(void* const* d_in, const int* in_sizes, int n_in,
                              void* d_out, int out_size, void* d_ws, size_t ws_size,
                              hipStream_t stream) {
    const float* x    = (const float*)d_in[0];
    const int*   ls   = (const int*)  d_in[1];
    const float* l1w  = (const float*)d_in[2];
    const float* l1b  = (const float*)d_in[3];
    const float* l1fw = (const float*)d_in[4];
    const float* l1fb = (const float*)d_in[5];
    const float* l2w  = (const float*)d_in[6];
    const float* l2b  = (const float*)d_in[7];
    const float* outw = (const float*)d_in[8];
    const float* outb = (const float*)d_in[9];
    float* out = (float*)d_out;

    char* ws = (char*)d_ws;
    float* wc       = (float*)ws;                       // 128*3072*4 = 1.5 MB
    float* y        = (float*)(ws + 1572864);           // 16384*16*4 = 1 MB
    int*   bucketArr= (int*)(ws + 1572864 + 1048576);   // 8*16384*4 = 512 KB
    int*   counts   = (int*)(ws + 1572864 + 1048576 + 524288);

    (void)hipMemsetAsync(counts, 0, 32, stream);
    k_combine<<<384, 256, 0, stream>>>(l1w, l1fw, wc);
    k_bucket<<<BATCH / 256, 256, 0, stream>>>(ls, counts, bucketArr);
    // max blocks = 16384/32 + 7 (ceil rounding across 8 buckets)
    k_gemm<<<519, 256, 0, stream>>>(x, wc, l1b, l1fb, bucketArr, counts, y);
    k_tail<<<BATCH * 32 / 256, 256, 0, stream>>>(y, ls, l2w, l2b, outw, outb, out);
}